// Round 10
// baseline (83.259 us; speedup 1.0000x reference)
//
#include <hip/hip_runtime.h>
#include <hip/hip_cooperative_groups.h>
#include <hip/hip_bf16.h>
#include <math.h>

namespace cg = cooperative_groups;

#define NB 8
#define NL 128
#define D_ATOM 256
#define DH 32       // d_hid
#define DAB 64      // 2*d_hid
#define K1 21
#define K2 30
#define KT 51       // K1+K2
#define ROWS (NB*NL) // 1024
#define LN_EPS 1e-5f

#define OUT1_ROW (NL*K1)      // 2688 floats
#define OUT2_ROW (NL*K2)      // 3840 floats
#define STAGE_N  (OUT1_ROW + OUT2_ROW) // 6528 floats
#define WCAT 1632             // 672 + 960 els per c
#define NWEL (DH*WCAT)        // 52224

typedef __attribute__((ext_vector_type(8))) short bf16x8;
typedef __attribute__((ext_vector_type(4))) float f32x4;

__device__ __forceinline__ unsigned short f2bf(float x) {
    __hip_bfloat16 h = __float2bfloat16(x);
    return *reinterpret_cast<unsigned short*>(&h);
}

// One cooperative kernel, 512 blocks x 256 threads, 2 blocks/CU.
// Stage 1: blocks 0..255: LN for 4 rows (verified R5 math) -> a_ws f32, bbf frags.
//          blocks 256..306: Wcat -> bf16 linear Wlin (coalesced copy).
// grid.sync()
// Stage 2: all blocks: R5 pair verbatim for 2 rows (T GEMV on bf16 W -> Tf LDS
//          -> 16 MFMA -> stg -> coalesced copyout).
__global__ __launch_bounds__(256, 2) void fused_kernel(
    const float* __restrict__ z, const float* __restrict__ W_in,
    const float* __restrict__ b_in, const float* __restrict__ ln_g,
    const float* __restrict__ ln_b, const float* __restrict__ W1,
    const float* __restrict__ W2, const float* __restrict__ b1v,
    const float* __restrict__ b2v, float* __restrict__ a_ws,
    unsigned short* __restrict__ bbf, unsigned short* __restrict__ Wlin,
    float* __restrict__ out)
{
    __shared__ __align__(16) unsigned char smem[69632]; // max(Wl+zl, Tf+stg)
    __shared__ float al[2][DH];

    const int t   = threadIdx.x;
    const int bid = blockIdx.x;

    // ---------------- stage 1 ----------------
    if (bid < 256) {
        float* Wl  = (float*)smem;                 // 16384 f32 (64 KB)
        float* zlf = (float*)(smem + 65536);       // 1024 f32 (4 KB)
        const int w = t >> 6, j = t & 63;
        const int row0s = bid * 4;

        #pragma unroll
        for (int s = 0; s < 16; ++s) {
            int i4 = t + s * 256;
            ((float4*)Wl)[i4] = ((const float4*)W_in)[i4];
        }
        ((float4*)zlf)[t] = ((const float4*)(z + (size_t)row0s * D_ATOM))[t];
        __syncthreads();

        float acc = b_in[j];
        #pragma unroll 8
        for (int i = 0; i < D_ATOM; ++i)
            acc = fmaf(zlf[w * D_ATOM + i], Wl[i * DAB + j], acc);

        float g = 0.5f * acc * (1.0f + erff(acc * 0.70710678118654752f));

        float s = g, sq = g * g;
        #pragma unroll
        for (int msk = 1; msk < 64; msk <<= 1) {
            s  += __shfl_xor(s,  msk, 64);
            sq += __shfl_xor(sq, msk, 64);
        }
        float mu  = s  * (1.0f / 64.0f);
        float var = sq * (1.0f / 64.0f) - mu * mu;
        float y = (g - mu) * rsqrtf(var + LN_EPS) * ln_g[j] + ln_b[j];

        const int row = row0s + w;
        if (j < DH) {
            a_ws[row * DH + j] = y;                // f32, coalesced
        } else {
            const int d = j - DH, m = row & 127, batch = row >> 7;
            bbf[batch * 4096 + ((m >> 4) << 9) +
                ((((m & 15) | ((d >> 3) << 4)) << 3) | (d & 7))] = f2bf(y);
        }
    } else if (bid < 307) {
        // Wlin[c*1632 + o] = bf16(o<672 ? W1[c*672+o] : W2[c*960+o-672])
        const int base = (bid - 256) * 1024;
        #pragma unroll
        for (int e = 0; e < 4; ++e) {
            int idx = base + e * 256 + t;          // < 52224 always
            int c = idx / WCAT, o = idx - c * WCAT;
            float v = (o < 672) ? W1[c * 672 + o] : W2[c * 960 + (o - 672)];
            Wlin[idx] = f2bf(v);
        }
    }

    cg::this_grid().sync();

    // ---------------- stage 2: pair for rows {bid*2, bid*2+1} ----------------
    unsigned short* Tf = (unsigned short*)smem;    // 4096 hw (8 KB)
    float* stg = (float*)(smem + 8192);            // 2*6528 f32 (51 KB)
    const int row0  = bid * 2;
    const int batch = row0 >> 7;
    const int w  = t >> 6, l = t & 63;
    const int lg = l >> 4, li = l & 15;

    #pragma unroll
    for (int s = 0; s < 8; ++s)
        ((unsigned int*)Tf)[t + s * 256] = 0u;     // pads k=51..63 stay 0
    if (t < 2 * DH) al[t >> 5][t & 31] = a_ws[row0 * DH + t];
    __syncthreads();

    // ---- phase 1: T GEMV (7 coalesced u16 streams from Wlin) ----
    {
        float tacc0[7], tacc1[7];
        const unsigned short* wp[7];
        int fidx[7];
        bool val[7];
        #pragma unroll
        for (int s = 0; s < 7; ++s) {
            int o = t + s * 256;
            val[s] = (o < WCAT);
            int oo = val[s] ? o : 0;
            int d, k;
            if (oo < 672) { d = oo / 21; k = oo % 21; }
            else { int o2 = oo - 672; d = o2 / 30; k = 21 + o2 % 30; }
            wp[s] = Wlin + oo;
            fidx[s] = (((k >> 4) * 64 + ((k & 15) | ((d >> 3) << 4))) << 3) | (d & 7);
            tacc0[s] = 0.f; tacc1[s] = 0.f;
        }
        #pragma unroll 4
        for (int c = 0; c < DH; ++c) {
            float ac0 = al[0][c], ac1 = al[1][c];
            #pragma unroll
            for (int s = 0; s < 7; ++s) {
                float wv = __uint_as_float(((unsigned)wp[s][c * WCAT]) << 16);
                tacc0[s] = fmaf(ac0, wv, tacc0[s]);
                tacc1[s] = fmaf(ac1, wv, tacc1[s]);
            }
        }
        #pragma unroll
        for (int s = 0; s < 7; ++s) {
            if (val[s]) {
                Tf[fidx[s]]        = f2bf(tacc0[s]);
                Tf[2048 + fidx[s]] = f2bf(tacc1[s]);
            }
        }
    }
    __syncthreads();

    // ---- phase 2: pair MFMA (verbatim R5) ----
    const int r  = w >> 1;            // row within pair
    const int mh = w & 1;             // m-half

    bf16x8 afr[4], bfr[4];
    #pragma unroll
    for (int i = 0; i < 4; ++i)
        afr[i] = ((const bf16x8*)bbf)[batch * 512 + (mh * 4 + i) * 64 + l];
    #pragma unroll
    for (int kt = 0; kt < 4; ++kt)
        bfr[kt] = ((const bf16x8*)Tf)[(r * 4 + kt) * 64 + l];

    float bias[4];
    #pragma unroll
    for (int kt = 0; kt < 4; ++kt) {
        int k = kt * 16 + li;
        bias[kt] = (k < K1) ? b1v[k] : (k < KT ? b2v[k - K1] : 0.f);
    }

    float* stg_r = stg + r * STAGE_N;
    #pragma unroll
    for (int i = 0; i < 4; ++i) {
        const int mbase = (mh * 4 + i) * 16 + lg * 4;
        #pragma unroll
        for (int kt = 0; kt < 4; ++kt) {
            f32x4 acc = __builtin_amdgcn_mfma_f32_16x16x32_bf16(
                afr[i], bfr[kt], (f32x4){0.f, 0.f, 0.f, 0.f}, 0, 0, 0);
            const int k = kt * 16 + li;
            if (k < K1) {
                #pragma unroll
                for (int q = 0; q < 4; ++q)
                    stg_r[(mbase + q) * K1 + k] = acc[q] + bias[kt];
            } else if (k < KT) {
                #pragma unroll
                for (int q = 0; q < 4; ++q)
                    stg_r[OUT1_ROW + (mbase + q) * K2 + (k - K1)] = acc[q] + bias[kt];
            }
        }
    }
    __syncthreads();

    // ---- phase 3: coalesced copy-out (verbatim R5) ----
    #pragma unroll
    for (int rr = 0; rr < 2; ++rr) {
        const int row = row0 + rr;
        float* o1 = out + (size_t)row * OUT1_ROW;
        float* o2 = out + (size_t)ROWS * OUT1_ROW + (size_t)row * OUT2_ROW;
        const float4* s1 = (const float4*)(stg + rr * STAGE_N);
        const float4* s2 = (const float4*)(stg + rr * STAGE_N + OUT1_ROW);
        for (int i4 = t; i4 < OUT1_ROW / 4; i4 += 256)
            ((float4*)o1)[i4] = s1[i4];
        for (int i4 = t; i4 < OUT2_ROW / 4; i4 += 256)
            ((float4*)o2)[i4] = s2[i4];
    }
}

extern "C" void kernel_launch(void* const* d_in, const int* in_sizes, int n_in,
                              void* d_out, int out_size, void* d_ws, size_t ws_size,
                              hipStream_t stream) {
    const float* z    = (const float*)d_in[0];
    const float* W_in = (const float*)d_in[1];
    const float* b_in = (const float*)d_in[2];
    const float* ln_g = (const float*)d_in[3];
    const float* ln_b = (const float*)d_in[4];
    const float* W1   = (const float*)d_in[5];
    const float* b1   = (const float*)d_in[6];
    const float* W2   = (const float*)d_in[7];
    const float* b2   = (const float*)d_in[8];
    float* out = (float*)d_out;

    float*          a_ws = (float*)d_ws;                   // 32768 f32 (128 KB)
    unsigned short* bbf  = (unsigned short*)(a_ws + 32768);// 32768 hw  (64 KB)
    unsigned short* Wlin = bbf + 32768;                    // 52224 hw (102 KB)

    void* args[] = { (void*)&z, (void*)&W_in, (void*)&b_in, (void*)&ln_g,
                     (void*)&ln_b, (void*)&W1, (void*)&W2, (void*)&b1,
                     (void*)&b2, (void*)&a_ws, (void*)&bbf, (void*)&Wlin,
                     (void*)&out };
    hipLaunchCooperativeKernel((const void*)fused_kernel, dim3(512), dim3(256),
                               args, 0, stream);
}

// Round 11
// 26.358 us; speedup vs baseline: 3.1587x; 3.1587x over previous
//
#include <hip/hip_runtime.h>
#include <hip/hip_bf16.h>
#include <math.h>

#define NB 8
#define NL 128
#define D_ATOM 256
#define DH 32       // d_hid
#define DAB 64      // 2*d_hid
#define K1 21
#define K2 30
#define KT 51       // K1+K2
#define ROWS (NB*NL) // 1024
#define LN_EPS 1e-5f

#define OUT1_ROW (NL*K1)      // 2688 floats
#define OUT2_ROW (NL*K2)      // 3840 floats
#define STAGE_N  (OUT1_ROW + OUT2_ROW) // 6528 floats
#define TROW_HW 2048          // per-row T fragments: 4 kt * 512 hw

typedef __attribute__((ext_vector_type(8))) short bf16x8;
typedef __attribute__((ext_vector_type(4))) float f32x4;

__device__ __forceinline__ unsigned short f2bf(float x) {
    __hip_bfloat16 h = __float2bfloat16(x);
    return *reinterpret_cast<unsigned short*>(&h);
}

// ---------------- Kernel 1: LN + T-GEMV (LDS-staged T stores) ----------------
// 4 rows per block, 256 blocks.
// LN (verified R9): ab = LN(gelu(z@W_in+b_in)); b-half -> bbf (A-frag u16),
// a-half -> al LDS (f32).
// T-GEMV (verified R9 math): T[rr][d][k] = sum_c al[rr][c]*Wcat[c][d][k],
// 7 coalesced f32 W streams. NEW: tacc -> LDS Tstage (scattered u16, reusing
// the dead W_in buffer), then coalesced uint4 copyout to T_ws.
__global__ __launch_bounds__(256) void ln_t_kernel(
    const float* __restrict__ z, const float* __restrict__ W_in,
    const float* __restrict__ b_in, const float* __restrict__ ln_g,
    const float* __restrict__ ln_b, const float* __restrict__ W1,
    const float* __restrict__ W2, unsigned short* __restrict__ bbf,
    unsigned short* __restrict__ T_ws)
{
    __shared__ __align__(16) unsigned char smem[69632]; // Wl 64K + zl 4K | Tstage 16K
    __shared__ float al[4][DH];
    float* Wl  = (float*)smem;
    float* zl  = (float*)(smem + 65536);
    unsigned short* Tst = (unsigned short*)smem;        // alias of Wl (dead after LN)

    const int t = threadIdx.x;
    const int w = t >> 6, j = t & 63;
    const int row0 = blockIdx.x * 4;

    #pragma unroll
    for (int s = 0; s < 16; ++s) {
        int i4 = t + s * 256;
        ((float4*)Wl)[i4] = ((const float4*)W_in)[i4];
    }
    ((float4*)zl)[t] = ((const float4*)(z + (size_t)row0 * D_ATOM))[t];
    __syncthreads();

    float acc = b_in[j];
    #pragma unroll 8
    for (int i = 0; i < D_ATOM; ++i)
        acc = fmaf(zl[w * D_ATOM + i], Wl[i * DAB + j], acc);

    float g = 0.5f * acc * (1.0f + erff(acc * 0.70710678118654752f));

    float s = g, sq = g * g;
    #pragma unroll
    for (int msk = 1; msk < 64; msk <<= 1) {
        s  += __shfl_xor(s,  msk, 64);
        sq += __shfl_xor(sq, msk, 64);
    }
    float mu  = s  * (1.0f / 64.0f);
    float var = sq * (1.0f / 64.0f) - mu * mu;
    float y = (g - mu) * rsqrtf(var + LN_EPS) * ln_g[j] + ln_b[j];

    const int row = row0 + w;
    if (j < DH) {
        al[w][j] = y;
    } else {
        const int d = j - DH, m = row & 127, batch = row >> 7;
        bbf[batch * 4096 + ((m >> 4) << 9) +
            ((((m & 15) | ((d >> 3) << 4)) << 3) | (d & 7))] = f2bf(y);
    }
    __syncthreads();   // al ready; Wl/zl reads complete -> Tst may overwrite

    // ---- T GEMV (R9 verbatim, f32 W, 7 coalesced streams, 4 row-accs) ----
    float tacc[7][4];
    const float* wptr[7];
    int wstr[7], fidx[7];
    bool val[7];
    #pragma unroll
    for (int s2 = 0; s2 < 7; ++s2) {
        int o = t + s2 * 256;
        val[s2] = (o < 1632);
        int oo = val[s2] ? o : 0;
        int d, k;
        if (oo < 672) {
            wptr[s2] = W1 + oo; wstr[s2] = 672;
            d = oo / 21; k = oo % 21;
        } else {
            int o2 = oo - 672;
            wptr[s2] = W2 + o2; wstr[s2] = 960;
            d = o2 / 30; k = 21 + o2 % 30;
        }
        fidx[s2] = ((k >> 4) << 9) + ((((k & 15) | ((d >> 3) << 4)) << 3) | (d & 7));
        #pragma unroll
        for (int rr = 0; rr < 4; ++rr) tacc[s2][rr] = 0.f;
    }
    #pragma unroll 4
    for (int c = 0; c < DH; ++c) {
        float a0 = al[0][c], a1 = al[1][c], a2 = al[2][c], a3 = al[3][c];
        #pragma unroll
        for (int s2 = 0; s2 < 7; ++s2) {
            float wv = wptr[s2][c * wstr[s2]];
            tacc[s2][0] = fmaf(a0, wv, tacc[s2][0]);
            tacc[s2][1] = fmaf(a1, wv, tacc[s2][1]);
            tacc[s2][2] = fmaf(a2, wv, tacc[s2][2]);
            tacc[s2][3] = fmaf(a3, wv, tacc[s2][3]);
        }
    }
    // scattered u16 stores go to LDS (cheap), not global
    #pragma unroll
    for (int s2 = 0; s2 < 7; ++s2) {
        if (val[s2]) {
            #pragma unroll
            for (int rr = 0; rr < 4; ++rr)
                Tst[rr * TROW_HW + fidx[s2]] = f2bf(tacc[s2][rr]);
        }
    }
    __syncthreads();

    // coalesced copyout: 4 rows x 2048 hw = 1024 uint4
    uint4* dst = (uint4*)(T_ws + (size_t)row0 * TROW_HW);
    const uint4* src = (const uint4*)Tst;
    #pragma unroll
    for (int e = 0; e < 4; ++e)
        dst[t + e * 256] = src[t + e * 256];
}

// ---------------- Kernel 2: pair product (R9 verbatim — verified) ----------------
// 2 rows per block, 512 blocks. LDS = stg only (51 KB).
// kt=3 pad lanes (k>=51) masked to zero in-register.
__global__ __launch_bounds__(256) void pair_kernel(
    const unsigned short* __restrict__ bbf, const unsigned short* __restrict__ T_ws,
    const float* __restrict__ b1v, const float* __restrict__ b2v,
    float* __restrict__ out)
{
    const int row0  = blockIdx.x * 2;
    const int batch = row0 >> 7;
    const int t     = threadIdx.x;
    const int w = t >> 6, l = t & 63;
    const int lg = l >> 4, li = l & 15;
    const int r = w >> 1;               // row within pair
    const int mh = w & 1;               // m-half

    __shared__ __align__(16) float stg[2][STAGE_N];   // 51 KB

    bf16x8 afr[4], bfr[4];
    #pragma unroll
    for (int i = 0; i < 4; ++i)
        afr[i] = ((const bf16x8*)bbf)[batch * 512 + (mh * 4 + i) * 64 + l];
    #pragma unroll
    for (int kt = 0; kt < 4; ++kt)
        bfr[kt] = ((const bf16x8*)T_ws)[(size_t)(row0 + r) * 256 + kt * 64 + l];

    if (li >= 3) {
        bf16x8 zz = {0, 0, 0, 0, 0, 0, 0, 0};
        bfr[3] = zz;
    }

    float bias[4];
    #pragma unroll
    for (int kt = 0; kt < 4; ++kt) {
        int k = kt * 16 + li;
        bias[kt] = (k < K1) ? b1v[k] : (k < KT ? b2v[k - K1] : 0.f);
    }

    #pragma unroll
    for (int i = 0; i < 4; ++i) {
        const int mbase = (mh * 4 + i) * 16 + lg * 4;
        #pragma unroll
        for (int kt = 0; kt < 4; ++kt) {
            f32x4 acc = __builtin_amdgcn_mfma_f32_16x16x32_bf16(
                afr[i], bfr[kt], (f32x4){0.f, 0.f, 0.f, 0.f}, 0, 0, 0);
            const int k = kt * 16 + li;
            if (k < K1) {
                #pragma unroll
                for (int q = 0; q < 4; ++q)
                    stg[r][(mbase + q) * K1 + k] = acc[q] + bias[kt];
            } else if (k < KT) {
                #pragma unroll
                for (int q = 0; q < 4; ++q)
                    stg[r][OUT1_ROW + (mbase + q) * K2 + (k - K1)] = acc[q] + bias[kt];
            }
        }
    }
    __syncthreads();

    #pragma unroll
    for (int rr = 0; rr < 2; ++rr) {
        const int row = row0 + rr;
        float* o1 = out + (size_t)row * OUT1_ROW;
        float* o2 = out + (size_t)ROWS * OUT1_ROW + (size_t)row * OUT2_ROW;
        const float4* s1 = (const float4*)stg[rr];
        const float4* s2 = (const float4*)(stg[rr] + OUT1_ROW);
        for (int i4 = t; i4 < OUT1_ROW / 4; i4 += 256)
            ((float4*)o1)[i4] = s1[i4];
        for (int i4 = t; i4 < OUT2_ROW / 4; i4 += 256)
            ((float4*)o2)[i4] = s2[i4];
    }
}

extern "C" void kernel_launch(void* const* d_in, const int* in_sizes, int n_in,
                              void* d_out, int out_size, void* d_ws, size_t ws_size,
                              hipStream_t stream) {
    const float* z    = (const float*)d_in[0];
    const float* W_in = (const float*)d_in[1];
    const float* b_in = (const float*)d_in[2];
    const float* ln_g = (const float*)d_in[3];
    const float* ln_b = (const float*)d_in[4];
    const float* W1   = (const float*)d_in[5];
    const float* b1   = (const float*)d_in[6];
    const float* W2   = (const float*)d_in[7];
    const float* b2   = (const float*)d_in[8];
    float* out = (float*)d_out;

    unsigned short* bbf  = (unsigned short*)d_ws;   // 32768 hw (64 KB)
    unsigned short* T_ws = bbf + 32768;             // 1024*2048 hw (4 MB)

    ln_t_kernel<<<256, 256, 0, stream>>>(z, W_in, b_in, ln_g, ln_b,
                                         W1, W2, bbf, T_ws);
    pair_kernel<<<ROWS / 2, 256, 0, stream>>>(bbf, T_ws, b1, b2, out);
}

// Round 12
// 23.152 us; speedup vs baseline: 3.5962x; 1.1385x over previous
//
#include <hip/hip_runtime.h>
#include <hip/hip_bf16.h>
#include <math.h>

#define NB 8
#define NL 128
#define D_ATOM 256
#define DH 32       // d_hid
#define DAB 64      // 2*d_hid
#define K1 21
#define K2 30
#define KT 51       // K1+K2
#define ROWS (NB*NL) // 1024
#define LN_EPS 1e-5f

#define OUT1_ROW (NL*K1)      // 2688 floats
#define OUT2_ROW (NL*K2)      // 3840 floats
#define STAGE_N  (OUT1_ROW + OUT2_ROW) // 6528 floats
#define WCAT 1632             // 672 + 960 els per c

typedef __attribute__((ext_vector_type(8))) short bf16x8;
typedef __attribute__((ext_vector_type(4))) float f32x4;

__device__ __forceinline__ unsigned short f2bf(float x) {
    __hip_bfloat16 h = __float2bfloat16(x);
    return *reinterpret_cast<unsigned short*>(&h);
}

// ---------------- Kernel 1: LN (blocks 0..255) + Wlin prep (256..268) --------
// LN: verified R5 math; a -> a_ws (f32 coalesced), b -> bbf (A-frag u16).
// Wlin prep: verified R10 stage-1 code (bf16 linear Wcat copy, coalesced).
__global__ __launch_bounds__(256) void ln_wprep_kernel(
    const float* __restrict__ z, const float* __restrict__ W_in,
    const float* __restrict__ b_in, const float* __restrict__ ln_g,
    const float* __restrict__ ln_b, const float* __restrict__ W1,
    const float* __restrict__ W2, float* __restrict__ a_ws,
    unsigned short* __restrict__ bbf, unsigned short* __restrict__ Wlin)
{
    const int t = threadIdx.x;

    if (blockIdx.x >= 256) {
        // Wlin[c*1632 + o] = bf16(o<672 ? W1[c*672+o] : W2[c*960+o-672])
        const int base = ((int)blockIdx.x - 256) * 4096;
        #pragma unroll
        for (int e = 0; e < 16; ++e) {
            int idx = base + e * 256 + t;
            if (idx < DH * WCAT) {
                int c = idx / WCAT, o = idx - c * WCAT;
                float v = (o < 672) ? W1[c * 672 + o] : W2[c * 960 + (o - 672)];
                Wlin[idx] = f2bf(v);
            }
        }
        return;
    }

    __shared__ float Wl[D_ATOM * DAB];   // 64 KB
    __shared__ float zl[4][D_ATOM];      // 4 KB
    const int w = t >> 6, j = t & 63;
    const int row0 = blockIdx.x * 4;

    #pragma unroll
    for (int s = 0; s < 16; ++s) {
        int i4 = t + s * 256;
        ((float4*)Wl)[i4] = ((const float4*)W_in)[i4];
    }
    ((float4*)zl)[t] = ((const float4*)(z + (size_t)row0 * D_ATOM))[t];
    __syncthreads();

    float acc = b_in[j];
    #pragma unroll 8
    for (int i = 0; i < D_ATOM; ++i)
        acc = fmaf(zl[w][i], Wl[i * DAB + j], acc);

    float g = 0.5f * acc * (1.0f + erff(acc * 0.70710678118654752f));

    float s = g, sq = g * g;
    #pragma unroll
    for (int msk = 1; msk < 64; msk <<= 1) {
        s  += __shfl_xor(s,  msk, 64);
        sq += __shfl_xor(sq, msk, 64);
    }
    float mu  = s  * (1.0f / 64.0f);
    float var = sq * (1.0f / 64.0f) - mu * mu;
    float y = (g - mu) * rsqrtf(var + LN_EPS) * ln_g[j] + ln_b[j];

    const int row = row0 + w;
    if (j < DH) {
        a_ws[row * DH + j] = y;          // f32, coalesced
    } else {
        const int d = j - DH, m = row & 127, batch = row >> 7;
        bbf[batch * 4096 + ((m >> 4) << 9) +
            ((((m & 15) | ((d >> 3) << 4)) << 3) | (d & 7))] = f2bf(y);
    }
}

// ---------------- Kernel 2: pair product (R10 stage-2, standalone) ----------
// 2 rows per block, 512 blocks, ~60 KB LDS -> 2 blocks/CU.
// Phase 1: T GEMV, 7 coalesced u16 streams from Wlin (half the W bytes of R5).
// Phase 2: 16 MFMA/wave (verified). Phase 3: stg + coalesced copyout (verified).
__global__ __launch_bounds__(256) void pair_kernel(
    const float* __restrict__ a_ws, const unsigned short* __restrict__ bbf,
    const unsigned short* __restrict__ Wlin, const float* __restrict__ b1v,
    const float* __restrict__ b2v, float* __restrict__ out)
{
    const int row0  = blockIdx.x * 2;
    const int batch = row0 >> 7;
    const int t     = threadIdx.x;
    const int w  = t >> 6, l = t & 63;
    const int lg = l >> 4, li = l & 15;

    __shared__ unsigned short Tf[2 * 4 * 64 * 8];    // 8 KB
    __shared__ __align__(16) float stg[2][STAGE_N];  // 51 KB
    __shared__ float al[2][DH];

    #pragma unroll
    for (int s = 0; s < 8; ++s)
        ((unsigned int*)Tf)[t + s * 256] = 0u;       // pads k=51..63 stay 0
    if (t < 2 * DH) al[t >> 5][t & 31] = a_ws[row0 * DH + t];
    __syncthreads();

    // ---- phase 1: T GEMV (bf16 Wlin; R10-verified) ----
    {
        float tacc0[7], tacc1[7];
        const unsigned short* wp[7];
        int fidx[7];
        bool val[7];
        #pragma unroll
        for (int s = 0; s < 7; ++s) {
            int o = t + s * 256;
            val[s] = (o < WCAT);
            int oo = val[s] ? o : 0;
            int d, k;
            if (oo < 672) { d = oo / 21; k = oo % 21; }
            else { int o2 = oo - 672; d = o2 / 30; k = 21 + o2 % 30; }
            wp[s] = Wlin + oo;
            fidx[s] = (((k >> 4) * 64 + ((k & 15) | ((d >> 3) << 4))) << 3) | (d & 7);
            tacc0[s] = 0.f; tacc1[s] = 0.f;
        }
        #pragma unroll 4
        for (int c = 0; c < DH; ++c) {
            float ac0 = al[0][c], ac1 = al[1][c];
            #pragma unroll
            for (int s = 0; s < 7; ++s) {
                float wv = __uint_as_float(((unsigned)wp[s][c * WCAT]) << 16);
                tacc0[s] = fmaf(ac0, wv, tacc0[s]);
                tacc1[s] = fmaf(ac1, wv, tacc1[s]);
            }
        }
        #pragma unroll
        for (int s = 0; s < 7; ++s) {
            if (val[s]) {
                Tf[fidx[s]]        = f2bf(tacc0[s]);
                Tf[2048 + fidx[s]] = f2bf(tacc1[s]);
            }
        }
    }
    __syncthreads();

    // ---- phase 2: pair MFMA (verified R5/R10) ----
    const int r  = w >> 1;            // row within pair
    const int mh = w & 1;             // m-half

    bf16x8 afr[4], bfr[4];
    #pragma unroll
    for (int i = 0; i < 4; ++i)
        afr[i] = ((const bf16x8*)bbf)[batch * 512 + (mh * 4 + i) * 64 + l];
    #pragma unroll
    for (int kt = 0; kt < 4; ++kt)
        bfr[kt] = ((const bf16x8*)Tf)[(r * 4 + kt) * 64 + l];

    float bias[4];
    #pragma unroll
    for (int kt = 0; kt < 4; ++kt) {
        int k = kt * 16 + li;
        bias[kt] = (k < K1) ? b1v[k] : (k < KT ? b2v[k - K1] : 0.f);
    }

    #pragma unroll
    for (int i = 0; i < 4; ++i) {
        const int mbase = (mh * 4 + i) * 16 + lg * 4;
        #pragma unroll
        for (int kt = 0; kt < 4; ++kt) {
            f32x4 acc = __builtin_amdgcn_mfma_f32_16x16x32_bf16(
                afr[i], bfr[kt], (f32x4){0.f, 0.f, 0.f, 0.f}, 0, 0, 0);
            const int k = kt * 16 + li;
            if (k < K1) {
                #pragma unroll
                for (int q = 0; q < 4; ++q)
                    stg[r][(mbase + q) * K1 + k] = acc[q] + bias[kt];
            } else if (k < KT) {
                #pragma unroll
                for (int q = 0; q < 4; ++q)
                    stg[r][OUT1_ROW + (mbase + q) * K2 + (k - K1)] = acc[q] + bias[kt];
            }
        }
    }
    __syncthreads();

    // ---- phase 3: coalesced copy-out (verified) ----
    #pragma unroll
    for (int rr = 0; rr < 2; ++rr) {
        const int row = row0 + rr;
        float* o1 = out + (size_t)row * OUT1_ROW;
        float* o2 = out + (size_t)ROWS * OUT1_ROW + (size_t)row * OUT2_ROW;
        const float4* s1 = (const float4*)stg[rr];
        const float4* s2 = (const float4*)(stg[rr] + OUT1_ROW);
        for (int i4 = t; i4 < OUT1_ROW / 4; i4 += 256)
            ((float4*)o1)[i4] = s1[i4];
        for (int i4 = t; i4 < OUT2_ROW / 4; i4 += 256)
            ((float4*)o2)[i4] = s2[i4];
    }
}

extern "C" void kernel_launch(void* const* d_in, const int* in_sizes, int n_in,
                              void* d_out, int out_size, void* d_ws, size_t ws_size,
                              hipStream_t stream) {
    const float* z    = (const float*)d_in[0];
    const float* W_in = (const float*)d_in[1];
    const float* b_in = (const float*)d_in[2];
    const float* ln_g = (const float*)d_in[3];
    const float* ln_b = (const float*)d_in[4];
    const float* W1   = (const float*)d_in[5];
    const float* b1   = (const float*)d_in[6];
    const float* W2   = (const float*)d_in[7];
    const float* b2   = (const float*)d_in[8];
    float* out = (float*)d_out;

    float*          a_ws = (float*)d_ws;                    // 32768 f32 (128 KB)
    unsigned short* bbf  = (unsigned short*)(a_ws + 32768); // 32768 hw (64 KB)
    unsigned short* Wlin = bbf + 32768;                     // 52224 hw (102 KB)

    ln_wprep_kernel<<<269, 256, 0, stream>>>(z, W_in, b_in, ln_g, ln_b,
                                             W1, W2, a_ws, bbf, Wlin);
    pair_kernel<<<ROWS / 2, 256, 0, stream>>>(a_ws, bbf, Wlin, b1, b2, out);
}

// Round 13
// 22.680 us; speedup vs baseline: 3.6710x; 1.0208x over previous
//
#include <hip/hip_runtime.h>
#include <hip/hip_bf16.h>
#include <math.h>

#define NB 8
#define NL 128
#define D_ATOM 256
#define DH 32       // d_hid
#define DAB 64      // 2*d_hid
#define K1 21
#define K2 30
#define KT 51       // K1+K2
#define ROWS (NB*NL) // 1024
#define LN_EPS 1e-5f

#define OUT1_ROW (NL*K1)      // 2688 floats
#define OUT2_ROW (NL*K2)      // 3840 floats
#define STAGE_N  (OUT1_ROW + OUT2_ROW) // 6528 floats
#define WCAT 1632             // 672 + 960 els per c

typedef __attribute__((ext_vector_type(8))) short bf16x8;
typedef __attribute__((ext_vector_type(4))) float f32x4;

__device__ __forceinline__ unsigned short f2bf(float x) {
    __hip_bfloat16 h = __float2bfloat16(x);
    return *reinterpret_cast<unsigned short*>(&h);
}

// ---------------- Kernel 1: LN (blocks 0..255) + Wlin2 prep (256..271) ------
// LN: verified math; a -> a_ws (f32), b -> bbf (A-frag u16).
// Wlin2: packed-for-consumer layout: Wlin2[(c*256+t)*8 + s] = bf16(Wcat[c][s*256+t])
//        (s=7 and out-of-range -> 0). Each pair-kernel thread then reads its
//        7 weights per c as ONE aligned uint4.
__global__ __launch_bounds__(256) void ln_wprep_kernel(
    const float* __restrict__ z, const float* __restrict__ W_in,
    const float* __restrict__ b_in, const float* __restrict__ ln_g,
    const float* __restrict__ ln_b, const float* __restrict__ W1,
    const float* __restrict__ W2, float* __restrict__ a_ws,
    unsigned short* __restrict__ bbf, unsigned short* __restrict__ Wlin2)
{
    const int t = threadIdx.x;

    if (blockIdx.x >= 256) {
        // 16 blocks * 256 threads * 2 pairs = 8192 (c,t2) pairs, uint4 each
        const int base = ((int)blockIdx.x - 256) * 512;
        #pragma unroll
        for (int e = 0; e < 2; ++e) {
            int p  = base + e * 256 + t;        // 0..8191
            int c  = p >> 8, t2 = p & 255;
            unsigned short v[8];
            #pragma unroll
            for (int s = 0; s < 8; ++s) {
                int o = s * 256 + t2;
                float val = 0.f;
                if (o < 672)       val = W1[c * 672 + o];
                else if (o < WCAT) val = W2[c * 960 + (o - 672)];
                v[s] = f2bf(val);
            }
            uint4 wq;
            wq.x = (unsigned)v[0] | ((unsigned)v[1] << 16);
            wq.y = (unsigned)v[2] | ((unsigned)v[3] << 16);
            wq.z = (unsigned)v[4] | ((unsigned)v[5] << 16);
            wq.w = (unsigned)v[6] | ((unsigned)v[7] << 16);
            ((uint4*)Wlin2)[p] = wq;
        }
        return;
    }

    __shared__ float Wl[D_ATOM * DAB];   // 64 KB
    __shared__ float zl[4][D_ATOM];      // 4 KB
    const int w = t >> 6, j = t & 63;
    const int row0 = blockIdx.x * 4;

    #pragma unroll
    for (int s = 0; s < 16; ++s) {
        int i4 = t + s * 256;
        ((float4*)Wl)[i4] = ((const float4*)W_in)[i4];
    }
    ((float4*)zl)[t] = ((const float4*)(z + (size_t)row0 * D_ATOM))[t];
    __syncthreads();

    float acc = b_in[j];
    #pragma unroll 8
    for (int i = 0; i < D_ATOM; ++i)
        acc = fmaf(zl[w][i], Wl[i * DAB + j], acc);

    float g = 0.5f * acc * (1.0f + erff(acc * 0.70710678118654752f));

    float s = g, sq = g * g;
    #pragma unroll
    for (int msk = 1; msk < 64; msk <<= 1) {
        s  += __shfl_xor(s,  msk, 64);
        sq += __shfl_xor(sq, msk, 64);
    }
    float mu  = s  * (1.0f / 64.0f);
    float var = sq * (1.0f / 64.0f) - mu * mu;
    float y = (g - mu) * rsqrtf(var + LN_EPS) * ln_g[j] + ln_b[j];

    const int row = row0 + w;
    if (j < DH) {
        a_ws[row * DH + j] = y;          // f32, coalesced
    } else {
        const int d = j - DH, m = row & 127, batch = row >> 7;
        bbf[batch * 4096 + ((m >> 4) << 9) +
            ((((m & 15) | ((d >> 3) << 4)) << 3) | (d & 7))] = f2bf(y);
    }
}

// ---------------- Kernel 2: pair product ----------------
// 2 rows per block, 512 blocks, 34.6 KB LDS -> 4 blocks/CU (16 waves/CU).
// Phase 1: T GEMV; each thread reads ONE uint4 of Wlin2 per c (7 weights).
// Phase 2/3: verified MFMA + single-row stage + coalesced copyout, twice.
__global__ __launch_bounds__(256, 4) void pair_kernel(
    const float* __restrict__ a_ws, const unsigned short* __restrict__ bbf,
    const unsigned short* __restrict__ Wlin2, const float* __restrict__ b1v,
    const float* __restrict__ b2v, float* __restrict__ out)
{
    const int row0  = blockIdx.x * 2;
    const int batch = row0 >> 7;
    const int t     = threadIdx.x;
    const int w  = t >> 6, l = t & 63;
    const int lg = l >> 4, li = l & 15;

    __shared__ unsigned short Tf[2 * 4 * 64 * 8];    // 8 KB
    __shared__ __align__(16) float stg[STAGE_N];     // 25.5 KB (one row)
    __shared__ float al[2][DH];

    #pragma unroll
    for (int s = 0; s < 8; ++s)
        ((unsigned int*)Tf)[t + s * 256] = 0u;       // pads k=51..63 stay 0
    if (t < 2 * DH) al[t >> 5][t & 31] = a_ws[row0 * DH + t];
    __syncthreads();

    // ---- phase 1: T GEMV (uint4-packed Wlin2) ----
    {
        float tacc0[7], tacc1[7];
        int fidx[7];
        bool val[7];
        #pragma unroll
        for (int s = 0; s < 7; ++s) {
            int o = t + s * 256;
            val[s] = (o < WCAT);
            int oo = val[s] ? o : 0;
            int d, k;
            if (oo < 672) { d = oo / 21; k = oo % 21; }
            else { int o2 = oo - 672; d = o2 / 30; k = 21 + o2 % 30; }
            fidx[s] = (((k >> 4) * 64 + ((k & 15) | ((d >> 3) << 4))) << 3) | (d & 7);
            tacc0[s] = 0.f; tacc1[s] = 0.f;
        }
        const uint4* wbase = ((const uint4*)Wlin2) + t;
        #pragma unroll 4
        for (int c = 0; c < DH; ++c) {
            float ac0 = al[0][c], ac1 = al[1][c];
            uint4 wq = wbase[c * 256];
            float wv[7];
            wv[0] = __uint_as_float(wq.x << 16);
            wv[1] = __uint_as_float(wq.x & 0xffff0000u);
            wv[2] = __uint_as_float(wq.y << 16);
            wv[3] = __uint_as_float(wq.y & 0xffff0000u);
            wv[4] = __uint_as_float(wq.z << 16);
            wv[5] = __uint_as_float(wq.z & 0xffff0000u);
            wv[6] = __uint_as_float(wq.w << 16);
            #pragma unroll
            for (int s = 0; s < 7; ++s) {
                tacc0[s] = fmaf(ac0, wv[s], tacc0[s]);
                tacc1[s] = fmaf(ac1, wv[s], tacc1[s]);
            }
        }
        #pragma unroll
        for (int s = 0; s < 7; ++s) {
            if (val[s]) {
                Tf[fidx[s]]        = f2bf(tacc0[s]);
                Tf[2048 + fidx[s]] = f2bf(tacc1[s]);
            }
        }
    }
    __syncthreads();

    // ---- phase 2/3: per-row MFMA + stage + copyout (verified math) ----
    const int r  = w >> 1;            // wave's row within pair
    const int mh = w & 1;             // m-half

    bf16x8 afr[4], bfr[4];
    #pragma unroll
    for (int i = 0; i < 4; ++i)
        afr[i] = ((const bf16x8*)bbf)[batch * 512 + (mh * 4 + i) * 64 + l];
    #pragma unroll
    for (int kt = 0; kt < 4; ++kt)
        bfr[kt] = ((const bf16x8*)Tf)[(r * 4 + kt) * 64 + l];

    float bias[4];
    #pragma unroll
    for (int kt = 0; kt < 4; ++kt) {
        int k = kt * 16 + li;
        bias[kt] = (k < K1) ? b1v[k] : (k < KT ? b2v[k - K1] : 0.f);
    }

    #pragma unroll
    for (int rr = 0; rr < 2; ++rr) {
        if (r == rr) {
            #pragma unroll
            for (int i = 0; i < 4; ++i) {
                const int mbase = (mh * 4 + i) * 16 + lg * 4;
                #pragma unroll
                for (int kt = 0; kt < 4; ++kt) {
                    f32x4 acc = __builtin_amdgcn_mfma_f32_16x16x32_bf16(
                        afr[i], bfr[kt], (f32x4){0.f, 0.f, 0.f, 0.f}, 0, 0, 0);
                    const int k = kt * 16 + li;
                    if (k < K1) {
                        #pragma unroll
                        for (int q = 0; q < 4; ++q)
                            stg[(mbase + q) * K1 + k] = acc[q] + bias[kt];
                    } else if (k < KT) {
                        #pragma unroll
                        for (int q = 0; q < 4; ++q)
                            stg[OUT1_ROW + (mbase + q) * K2 + (k - K1)] = acc[q] + bias[kt];
                    }
                }
            }
        }
        __syncthreads();

        const int row = row0 + rr;
        float* o1 = out + (size_t)row * OUT1_ROW;
        float* o2 = out + (size_t)ROWS * OUT1_ROW + (size_t)row * OUT2_ROW;
        const float4* s1 = (const float4*)stg;
        const float4* s2 = (const float4*)(stg + OUT1_ROW);
        for (int i4 = t; i4 < OUT1_ROW / 4; i4 += 256)
            ((float4*)o1)[i4] = s1[i4];
        for (int i4 = t; i4 < OUT2_ROW / 4; i4 += 256)
            ((float4*)o2)[i4] = s2[i4];
        if (rr == 0) __syncthreads();   // stg reused by row 1
    }
}

extern "C" void kernel_launch(void* const* d_in, const int* in_sizes, int n_in,
                              void* d_out, int out_size, void* d_ws, size_t ws_size,
                              hipStream_t stream) {
    const float* z    = (const float*)d_in[0];
    const float* W_in = (const float*)d_in[1];
    const float* b_in = (const float*)d_in[2];
    const float* ln_g = (const float*)d_in[3];
    const float* ln_b = (const float*)d_in[4];
    const float* W1   = (const float*)d_in[5];
    const float* b1   = (const float*)d_in[6];
    const float* W2   = (const float*)d_in[7];
    const float* b2   = (const float*)d_in[8];
    float* out = (float*)d_out;

    float*          a_ws  = (float*)d_ws;                    // 32768 f32 (128 KB)
    unsigned short* bbf   = (unsigned short*)(a_ws + 32768); // 32768 hw (64 KB)
    unsigned short* Wlin2 = bbf + 32768;                     // 65536 hw (128 KB)

    ln_wprep_kernel<<<272, 256, 0, stream>>>(z, W_in, b_in, ln_g, ln_b,
                                             W1, W2, a_ws, bbf, Wlin2);
    pair_kernel<<<ROWS / 2, 256, 0, stream>>>(a_ws, bbf, Wlin2, b1, b2, out);
}